// Round 3
// baseline (261.246 us; speedup 1.0000x reference)
//
#include <hip/hip_runtime.h>

#define D 32
#define EPS 1e-5f
#define TPB 256
#define NB 256          // blocks for streaming passes

// ======================================================================
// NEW PATH v3: dst-sorted edges, per-thread W gather, LDS segment reduce
//   memset(80KB) -> g1_hist -> g2_scan -> g3_scatter -> g4_main -> g5_final
// ======================================================================

// ---- G1: zero `out` + per-dst histogram ------------------------------
__global__ void g1_hist(const int* __restrict__ dst, int E, int N,
                        float* __restrict__ out, int* __restrict__ cnt)
{
    const int gid = blockIdx.x * TPB + threadIdx.x;
    const int stride = gridDim.x * TPB;
    for (int i = gid; i < N * D; i += stride) out[i] = 0.f;
    for (int e = gid; e < E; e += stride) atomicAdd(&cnt[dst[e]], 1);
}

// ---- G2: dst exclusive scan over N bins (single block, 1024 thr) -----
// (structure verified correct in R2's k2_scan)
__global__ __launch_bounds__(1024)
void g2_scan(const int* __restrict__ cnt, int N, int E,
             int* __restrict__ dst_base, int* __restrict__ cursor_dst)
{
    const int t = threadIdx.x;
    __shared__ int sb[1024];
    const int chunk = (N + 1023) >> 10;
    const int lo = t * chunk, hi = min(N, lo + chunk);
    int part = 0;
    for (int i = lo; i < hi; ++i) part += cnt[i];
    sb[t] = part;
    __syncthreads();
    for (int off = 1; off < 1024; off <<= 1) {
        const int v = (t >= off) ? sb[t - off] : 0;
        __syncthreads();
        sb[t] += v;
        __syncthreads();
    }
    int base = sb[t] - part;            // exclusive prefix of this chunk
    for (int i = lo; i < hi; ++i) {
        dst_base[i]   = base;
        cursor_dst[i] = base;
        base += cnt[i];
    }
    if (t == 0) dst_base[N] = E;
}

// ---- G3: scatter edges into dst-sorted order -------------------------
__global__ void g3_scatter(const int* __restrict__ src, const int* __restrict__ dst,
                           const int* __restrict__ etype, int E,
                           int* __restrict__ cursor_dst,
                           int* __restrict__ ssrc, int* __restrict__ sdst,
                           int* __restrict__ setype)
{
    const int gid = blockIdx.x * TPB + threadIdx.x;
    const int stride = gridDim.x * TPB;
    for (int e = gid; e < E; e += stride) {
        const int dnode = dst[e];
        const int p = atomicAdd(&cursor_dst[dnode], 1);   // dst-order slot
        ssrc[p]   = src[e];
        sdst[p]   = dnode;
        setype[p] = etype[e];
    }
}

// ---- G4: per-edge GEMV + relu + per-dim stats + LDS segment reduce ---
__global__ __launch_bounds__(TPB)
void g4_main(const float* __restrict__ h, const float* __restrict__ W,
             const int* __restrict__ ssrc, const int* __restrict__ sdst,
             const int* __restrict__ setype, int E,
             float* __restrict__ out,
             float* __restrict__ stat_sum, float* __restrict__ stat_sq)
{
    __shared__ float s_tile[TPB * 33];
    __shared__ int   s_dst[TPB];
    __shared__ int   s_flag[TPB];
    __shared__ int   s_segstart[TPB];
    __shared__ float s_aux[2 * TPB];
    __shared__ int   s_nseg;

    const int tid   = threadIdx.x;
    const int start = blockIdx.x * TPB;
    const int nE    = min(TPB, E - start);
    const int p     = start + tid;

    if (tid == 0) s_nseg = 0;
    if (tid < nE) s_dst[tid] = sdst[p];
    __syncthreads();

    if (tid < nE) {
        const int et = setype[p];
        const int s  = ssrc[p];
        const float* Wr = W + (size_t)et * (D * D);

        float hbuf[D];
        const float4* hp = (const float4*)(h + (size_t)s * D);
#pragma unroll
        for (int c = 0; c < D / 4; ++c) {
            const float4 hv = hp[c];
            hbuf[4 * c]     = hv.x; hbuf[4 * c + 1] = hv.y;
            hbuf[4 * c + 2] = hv.z; hbuf[4 * c + 3] = hv.w;
        }

        float acc[D];
#pragma unroll
        for (int o = 0; o < D; ++o) acc[o] = 0.f;

        const float4* wp = (const float4*)Wr;
#pragma unroll 4
        for (int d = 0; d < D; ++d) {
            const float hd = hbuf[d];
#pragma unroll
            for (int c = 0; c < D / 4; ++c) {
                const float4 wv = wp[d * (D / 4) + c];
                acc[4 * c]     = fmaf(hd, wv.x, acc[4 * c]);
                acc[4 * c + 1] = fmaf(hd, wv.y, acc[4 * c + 1]);
                acc[4 * c + 2] = fmaf(hd, wv.z, acc[4 * c + 2]);
                acc[4 * c + 3] = fmaf(hd, wv.w, acc[4 * c + 3]);
            }
        }
#pragma unroll
        for (int o = 0; o < D; ++o)
            s_tile[tid * 33 + o] = fmaxf(acc[o], 0.f);
        s_flag[tid] = (tid == 0) || (s_dst[tid] != s_dst[tid - 1]);
    }
    __syncthreads();

    if (tid < nE && s_flag[tid]) {
        const int si = atomicAdd(&s_nseg, 1);   // LDS atomic, order irrelevant
        s_segstart[si] = tid;
    }

    // per-dim BN stat partials (o = i&31 fixed per element -> correct dims)
    float ps = 0.f, pq = 0.f;
    for (int i = tid; i < nE * D; i += TPB) {
        const int row = i >> 5, o = i & 31;
        const float v = s_tile[row * 33 + o];
        ps += v; pq += v * v;
    }
    s_aux[tid]       = ps;
    s_aux[TPB + tid] = pq;
    __syncthreads();                 // covers s_aux AND s_segstart/s_nseg

    if (tid < D) {
        float ss = 0.f, sq = 0.f;
#pragma unroll
        for (int c = 0; c < TPB / D; ++c) {
            ss += s_aux[c * D + tid];
            sq += s_aux[TPB + c * D + tid];
        }
        atomicAdd(&stat_sum[tid], ss);
        atomicAdd(&stat_sq[tid], sq);
    }

    // segment sums: one (segment, dim) per worker; one atomic per pair
    const int o = tid & (D - 1);
    const int nseg = s_nseg;
    for (int si = tid >> 5; si < nseg; si += TPB / D) {
        const int st   = s_segstart[si];
        const int node = s_dst[st];
        float sum = 0.f;
        for (int row = st; row < nE; ++row) {
            if (row > st && s_flag[row]) break;
            sum += s_tile[row * 33 + o];
        }
        atomicAdd(&out[(size_t)node * D + o], sum);
    }
}

// ---- G5: BN affine folded into segment mean --------------------------
__global__ void g5_final(float* __restrict__ out, const int* __restrict__ dst_base,
                         const float* __restrict__ stat_sum,
                         const float* __restrict__ stat_sq,
                         const float* __restrict__ gamma,
                         const float* __restrict__ beta,
                         float invE, int N)
{
    const int i = blockIdx.x * TPB + threadIdx.x;
    if (i >= N * D) return;
    const int o    = i & 31;
    const int node = i >> 5;
    const float mu  = stat_sum[o] * invE;
    const float var = fmaxf(stat_sq[o] * invE - mu * mu, 0.f);
    const float is  = rsqrtf(var + EPS);
    const float sc  = gamma[o] * is;
    const float sh  = fmaf(-mu, sc, beta[o]);
    const float c   = (float)(dst_base[node + 1] - dst_base[node]);
    out[i] = fmaf(out[i], sc, sh * c) / fmaxf(c, 1.0f);
}

// ======================================================================
// OLD PATH (fallback when workspace is too small) — unchanged, verified
// ======================================================================

__global__ void hist2_kernel(const int* __restrict__ etype, int E, int R, int chunk,
                             int* __restrict__ blockHistT)   // [R][NB]
{
    __shared__ int lh[1024];
    for (int i = threadIdx.x; i < R; i += TPB) lh[i] = 0;
    __syncthreads();
    const int lo = blockIdx.x * chunk, hi = min(E, lo + chunk);
    for (int e = lo + threadIdx.x; e < hi; e += TPB)
        atomicAdd(&lh[etype[e]], 1);
    __syncthreads();
    for (int r = threadIdx.x; r < R; r += TPB)
        blockHistT[r * NB + blockIdx.x] = lh[r];
}

__global__ void scan2_kernel(int* __restrict__ blockHistT, int R,
                             int* __restrict__ rel_start,
                             int* __restrict__ task_rel, int* __restrict__ task_start,
                             int* __restrict__ n_tasks)
{
    __shared__ int tot[1024];
    __shared__ int s_start[1025];
    __shared__ int s_tbase[1024];
    const int r = threadIdx.x;
    if (r < R) {
        int acc = 0;
        int* p = blockHistT + r * NB;
        for (int b = 0; b < NB; ++b) { int v = p[b]; p[b] = acc; acc += v; }
        tot[r] = acc;
    }
    __syncthreads();
    if (threadIdx.x == 0) {
        int acc = 0, tb = 0;
        for (int rr = 0; rr < R; ++rr) {
            s_start[rr] = acc; s_tbase[rr] = tb;
            acc += tot[rr];
            tb  += (tot[rr] + TPB - 1) / TPB;
        }
        s_start[R] = acc;
        rel_start[R] = acc;
        *n_tasks = tb;
    }
    __syncthreads();
    if (r < R) {
        const int st = s_start[r];
        rel_start[r] = st;
        const int nb = (tot[r] + TPB - 1) / TPB;
        const int tb = s_tbase[r];
        for (int b = 0; b < nb; ++b) {
            task_rel[tb + b]   = r;
            task_start[tb + b] = st + b * TPB;
        }
    }
}

__global__ void scatter2_kernel(const int* __restrict__ src, const int* __restrict__ dst,
                                const int* __restrict__ etype, int E, int R, int chunk,
                                const int* __restrict__ blockHistT,
                                const int* __restrict__ rel_start,
                                int* __restrict__ ssrc, int* __restrict__ sdst)
{
    __shared__ int cur[1024];
    for (int r = threadIdx.x; r < R; r += TPB)
        cur[r] = rel_start[r] + blockHistT[r * NB + blockIdx.x];
    __syncthreads();
    const int lo = blockIdx.x * chunk, hi = min(E, lo + chunk);
    for (int e = lo + threadIdx.x; e < hi; e += TPB) {
        const int p = atomicAdd(&cur[etype[e]], 1);   // LDS atomic only
        ssrc[p] = src[e];
        sdst[p] = dst[e];
    }
}

__global__ __launch_bounds__(TPB)
void rgcn_main(const float* __restrict__ h, const float* __restrict__ W,
               const int* __restrict__ rel_start,
               const int* __restrict__ task_rel, const int* __restrict__ task_start,
               const int* __restrict__ n_tasks_p,
               const int* __restrict__ ssrc, const int* __restrict__ sdst,
               float* __restrict__ out,
               float* __restrict__ stat_sum, float* __restrict__ stat_sq,
               float* __restrict__ cnt)
{
    __shared__ float s_tile[TPB * 33];
    __shared__ int   s_src[TPB];
    __shared__ int   s_dst[TPB];
    __shared__ float s_aux[2 * TPB];

    const int task = blockIdx.x;
    if (task >= *n_tasks_p) return;
    const int r      = task_rel[task];
    const int start  = task_start[task];
    const int relEnd = rel_start[r + 1];
    const int nE     = min(TPB, relEnd - start);
    const int tid    = threadIdx.x;

    if (tid < nE) {
        s_src[tid] = ssrc[start + tid];
        s_dst[tid] = sdst[start + tid];
    }
    __syncthreads();

    for (int i = tid; i < nE * 8; i += TPB) {
        const int row = i >> 3, seg = i & 7;
        const float4 v = *(const float4*)(h + (size_t)s_src[row] * D + seg * 4);
        float* p = &s_tile[row * 33 + seg * 4];
        p[0] = v.x; p[1] = v.y; p[2] = v.z; p[3] = v.w;
    }
    __syncthreads();

    const float* Wr = W + (size_t)__builtin_amdgcn_readfirstlane(r) * (D * D);

    float acc[D];
#pragma unroll
    for (int o = 0; o < D; ++o) acc[o] = 0.f;

    if (tid < nE) {
#pragma unroll 4
        for (int d = 0; d < D; ++d) {
            const float hd = s_tile[tid * 33 + d];
#pragma unroll
            for (int o = 0; o < D; ++o)
                acc[o] = fmaf(hd, Wr[d * D + o], acc[o]);
        }
#pragma unroll
        for (int o = 0; o < D; ++o) acc[o] = fmaxf(acc[o], 0.f);
        atomicAdd(&cnt[s_dst[tid]], 1.0f);
    }
    __syncthreads();

    if (tid < nE) {
#pragma unroll
        for (int o = 0; o < D; ++o) s_tile[tid * 33 + o] = acc[o];
    }
    __syncthreads();

    float ps = 0.f, pq = 0.f;
    for (int i = tid; i < nE * D; i += TPB) {
        const int row = i >> 5, o = i & 31;
        const float v = s_tile[row * 33 + o];
        atomicAdd(&out[(size_t)s_dst[row] * D + o], v);
        ps += v; pq += v * v;
    }
    s_aux[tid]       = ps;
    s_aux[TPB + tid] = pq;
    __syncthreads();
    if (tid < D) {
        float ss = 0.f, sq = 0.f;
#pragma unroll
        for (int c = 0; c < TPB / D; ++c) {
            ss += s_aux[c * D + tid];
            sq += s_aux[TPB + c * D + tid];
        }
        atomicAdd(&stat_sum[tid], ss);
        atomicAdd(&stat_sq[tid], sq);
    }
}

__global__ void finalize_kernel(float* __restrict__ out, const float* __restrict__ cnt,
                                const float* __restrict__ stat_sum,
                                const float* __restrict__ stat_sq,
                                const float* __restrict__ gamma,
                                const float* __restrict__ beta,
                                float invE, int total)
{
    const int i = blockIdx.x * TPB + threadIdx.x;
    if (i >= total) return;
    const int o    = i & 31;
    const int node = i >> 5;
    const float mu  = stat_sum[o] * invE;
    const float var = fmaxf(stat_sq[o] * invE - mu * mu, 0.f);
    const float is  = rsqrtf(var + EPS);
    const float sc  = gamma[o] * is;
    const float sh  = fmaf(-mu, sc, beta[o]);
    const float c   = cnt[node];
    out[i] = fmaf(out[i], sc, sh * c) / fmaxf(c, 1.0f);
}

// ======================================================================
extern "C" void kernel_launch(void* const* d_in, const int* in_sizes, int n_in,
                              void* d_out, int out_size, void* d_ws, size_t ws_size,
                              hipStream_t stream)
{
    const float* h     = (const float*)d_in[0];
    const float* W     = (const float*)d_in[1];
    const float* gamma = (const float*)d_in[2];
    const float* beta  = (const float*)d_in[3];
    const int*   src   = (const int*)d_in[4];
    const int*   dst   = (const int*)d_in[5];
    const int*   etype = (const int*)d_in[6];
    float* out = (float*)d_out;

    const int E = in_sizes[4];
    const int N = in_sizes[0] / D;
    const int R = in_sizes[1] / (D * D);

    // ---------------- v3 workspace layout (dword offsets) ----------------
    const size_t o_stat_sum   = 0;
    const size_t o_stat_sq    = o_stat_sum + D;
    const size_t o_cnt        = o_stat_sq + D;
    const size_t zwords       = o_cnt + (size_t)N;          // zeroed prefix
    const size_t o_dst_base   = zwords;
    const size_t o_cursor_dst = o_dst_base + N + 1;
    const size_t o_ssrc       = o_cursor_dst + N;
    const size_t o_sdst       = o_ssrc + (size_t)E;
    const size_t o_setype     = o_sdst + (size_t)E;
    const size_t total_words  = o_setype + (size_t)E;

    if (ws_size >= total_words * 4) {
        // ------------------------- NEW PATH v3 ---------------------------
        float* stat_sum   = (float*)d_ws + o_stat_sum;
        float* stat_sq    = (float*)d_ws + o_stat_sq;
        int*   cnt        = (int*)d_ws + o_cnt;
        int*   dst_base   = (int*)d_ws + o_dst_base;
        int*   cursor_dst = (int*)d_ws + o_cursor_dst;
        int*   ssrc       = (int*)d_ws + o_ssrc;
        int*   sdst       = (int*)d_ws + o_sdst;
        int*   setype     = (int*)d_ws + o_setype;

        hipMemsetAsync(d_ws, 0, zwords * 4, stream);

        g1_hist<<<NB, TPB, 0, stream>>>(dst, E, N, out, cnt);
        g2_scan<<<1, 1024, 0, stream>>>(cnt, N, E, dst_base, cursor_dst);
        g3_scatter<<<NB, TPB, 0, stream>>>(src, dst, etype, E,
                                           cursor_dst, ssrc, sdst, setype);
        g4_main<<<(E + TPB - 1) / TPB, TPB, 0, stream>>>(
            h, W, ssrc, sdst, setype, E, out, stat_sum, stat_sq);
        g5_final<<<(N * D + TPB - 1) / TPB, TPB, 0, stream>>>(
            out, dst_base, stat_sum, stat_sq, gamma, beta,
            1.0f / (float)E, N);
        return;
    }

    // --------------------------- OLD PATH --------------------------------
    const int T = R + (E + TPB - 1) / TPB;        // max task count
    const int chunk = (E + NB - 1) / NB;

    float* stat_sum  = (float*)d_ws;
    float* stat_sq   = stat_sum + D;
    float* cntf      = stat_sq + D;
    int*   rel_start = (int*)(cntf + N);
    int*   n_tasks   = rel_start + R + 1;
    int*   task_rel  = n_tasks + 1;
    int*   task_start= task_rel + T;
    int*   blockHistT= task_start + T;
    int*   ssrc      = blockHistT + R * NB;
    int*   sdst      = ssrc + E;

    hipMemsetAsync(d_ws, 0, sizeof(float) * (size_t)(2 * D + N), stream);
    hipMemsetAsync(d_out, 0, sizeof(float) * (size_t)out_size, stream);

    hist2_kernel<<<NB, TPB, 0, stream>>>(etype, E, R, chunk, blockHistT);
    scan2_kernel<<<1, TPB, 0, stream>>>(blockHistT, R, rel_start,
                                        task_rel, task_start, n_tasks);
    scatter2_kernel<<<NB, TPB, 0, stream>>>(src, dst, etype, E, R, chunk,
                                            blockHistT, rel_start, ssrc, sdst);
    rgcn_main<<<T, TPB, 0, stream>>>(h, W, rel_start, task_rel, task_start,
                                     n_tasks, ssrc, sdst, out,
                                     stat_sum, stat_sq, cntf);
    finalize_kernel<<<(N * D + TPB - 1) / TPB, TPB, 0, stream>>>(
        out, cntf, stat_sum, stat_sq, gamma, beta, 1.0f / (float)E, N * D);
}

// Round 4
// 197.095 us; speedup vs baseline: 1.3255x; 1.3255x over previous
//
#include <hip/hip_runtime.h>

#define D 32
#define EPS 1e-5f
#define TPB 256
#define NB 256          // blocks for the counting-sort passes (fixed chunking)

// ======================================================================
// PATH v4: rel-sorted compute (wave-uniform W, as R0) + plain stores to
// rel-ordered msg + dst-segment gather-reduce via perm.
//   memset(small) -> hist3 -> scan3 -> scatter3 -> rgcn_main3 -> reduce3
// ======================================================================

// ---- S1: per-block rel histogram (transposed) + global dst counts ----
__global__ void hist3_kernel(const int* __restrict__ etype, const int* __restrict__ dst,
                             int E, int R, int chunk,
                             int* __restrict__ blockHistT,   // [R][NB]
                             int* __restrict__ cnt)          // [N]
{
    __shared__ int lh[1024];
    for (int i = threadIdx.x; i < R; i += TPB) lh[i] = 0;
    __syncthreads();
    const int lo = blockIdx.x * chunk, hi = min(E, lo + chunk);
    for (int e = lo + threadIdx.x; e < hi; e += TPB) {
        atomicAdd(&lh[etype[e]], 1);
        atomicAdd(&cnt[dst[e]], 1);
    }
    __syncthreads();
    for (int r = threadIdx.x; r < R; r += TPB)
        blockHistT[r * NB + blockIdx.x] = lh[r];
}

// ---- S2: rel scan (verified R0 structure) + dst scan (verified g2) ---
__global__ __launch_bounds__(1024)
void scan3_kernel(int* __restrict__ blockHistT, int R, int N, int E,
                  int* __restrict__ rel_start,
                  int* __restrict__ task_rel, int* __restrict__ task_start,
                  int* __restrict__ n_tasks,
                  const int* __restrict__ cnt,
                  int* __restrict__ dst_base, int* __restrict__ cursor_dst)
{
    const int t = threadIdx.x;
    __shared__ int tot[1024];
    __shared__ int s_start[1025];
    __shared__ int s_tbase[1024];
    __shared__ int sb[1024];

    // per-relation: in-place exclusive prefix of blockHistT rows
    if (t < R) {
        int acc = 0;
        int* p = blockHistT + t * NB;
        for (int b = 0; b < NB; ++b) { int v = p[b]; p[b] = acc; acc += v; }
        tot[t] = acc;
    }
    __syncthreads();
    if (t == 0) {
        int acc = 0, tb = 0;
        for (int rr = 0; rr < R; ++rr) {
            s_start[rr] = acc; s_tbase[rr] = tb;
            acc += tot[rr];
            tb  += (tot[rr] + TPB - 1) / TPB;
        }
        s_start[R] = acc;
        rel_start[R] = acc;
        *n_tasks = tb;
    }
    __syncthreads();
    if (t < R) {
        const int st = s_start[t];
        rel_start[t] = st;
        const int nb = (tot[t] + TPB - 1) / TPB;
        const int tb = s_tbase[t];
        for (int b = 0; b < nb; ++b) {
            task_rel[tb + b]   = t;
            task_start[tb + b] = st + b * TPB;
        }
    }

    // dst exclusive scan over N bins (chunk per thread + Hillis-Steele)
    const int chunk = (N + 1023) >> 10;
    const int lo = t * chunk, hi = min(N, lo + chunk);
    int part = 0;
    for (int i = lo; i < hi; ++i) part += cnt[i];
    sb[t] = part;
    __syncthreads();
    for (int off = 1; off < 1024; off <<= 1) {
        const int v = (t >= off) ? sb[t - off] : 0;
        __syncthreads();
        sb[t] += v;
        __syncthreads();
    }
    int base = sb[t] - part;            // exclusive prefix of this chunk
    for (int i = lo; i < hi; ++i) {
        dst_base[i]   = base;
        cursor_dst[i] = base;
        base += cnt[i];
    }
    if (t == 0) dst_base[N] = E;
}

// ---- S3: scatter into rel-sorted order + dst-order perm --------------
__global__ void scatter3_kernel(const int* __restrict__ src, const int* __restrict__ dst,
                                const int* __restrict__ etype, int E, int R, int chunk,
                                const int* __restrict__ blockHistT,
                                const int* __restrict__ rel_start,
                                int* __restrict__ cursor_dst,
                                int* __restrict__ ssrc, int* __restrict__ perm)
{
    __shared__ int cur[1024];
    for (int r = threadIdx.x; r < R; r += TPB)
        cur[r] = rel_start[r] + blockHistT[r * NB + blockIdx.x];
    __syncthreads();
    const int lo = blockIdx.x * chunk, hi = min(E, lo + chunk);
    for (int e = lo + threadIdx.x; e < hi; e += TPB) {
        const int p = atomicAdd(&cur[etype[e]], 1);        // LDS atomic
        ssrc[p] = src[e];
        const int q = atomicAdd(&cursor_dst[dst[e]], 1);   // dst-order slot
        perm[q] = p;                                       // dst-order -> rel-order
    }
}

// ---- MAIN: R0's verified rgcn_main, output atomics -> plain stores ---
__global__ __launch_bounds__(TPB)
void rgcn_main3(const float* __restrict__ h, const float* __restrict__ W,
                const int* __restrict__ rel_start,
                const int* __restrict__ task_rel, const int* __restrict__ task_start,
                const int* __restrict__ n_tasks_p,
                const int* __restrict__ ssrc,
                float* __restrict__ msg,
                float* __restrict__ stat_sum, float* __restrict__ stat_sq)
{
    __shared__ float s_tile[TPB * 33];
    __shared__ int   s_src[TPB];
    __shared__ float s_aux[2 * TPB];

    const int task = blockIdx.x;
    if (task >= *n_tasks_p) return;
    const int r      = task_rel[task];
    const int start  = task_start[task];
    const int relEnd = rel_start[r + 1];
    const int nE     = min(TPB, relEnd - start);
    const int tid    = threadIdx.x;

    if (tid < nE) s_src[tid] = ssrc[start + tid];
    __syncthreads();

    for (int i = tid; i < nE * 8; i += TPB) {
        const int row = i >> 3, seg = i & 7;
        const float4 v = *(const float4*)(h + (size_t)s_src[row] * D + seg * 4);
        float* p = &s_tile[row * 33 + seg * 4];
        p[0] = v.x; p[1] = v.y; p[2] = v.z; p[3] = v.w;
    }
    __syncthreads();

    const float* Wr = W + (size_t)__builtin_amdgcn_readfirstlane(r) * (D * D);

    float acc[D];
#pragma unroll
    for (int o = 0; o < D; ++o) acc[o] = 0.f;

    if (tid < nE) {
#pragma unroll 4
        for (int d = 0; d < D; ++d) {
            const float hd = s_tile[tid * 33 + d];
#pragma unroll
            for (int o = 0; o < D; ++o)
                acc[o] = fmaf(hd, Wr[d * D + o], acc[o]);
        }
#pragma unroll
        for (int o = 0; o < D; ++o) acc[o] = fmaxf(acc[o], 0.f);
    }
    __syncthreads();

    if (tid < nE) {
#pragma unroll
        for (int o = 0; o < D; ++o) s_tile[tid * 33 + o] = acc[o];
    }
    __syncthreads();

    // coalesced plain stores: i = row*32 + o is exactly the msg offset
    float* mbase = msg + (size_t)start * D;
    float ps = 0.f, pq = 0.f;
    for (int i = tid; i < nE * D; i += TPB) {
        const int row = i >> 5, o = i & 31;
        const float v = s_tile[row * 33 + o];
        mbase[i] = v;
        ps += v; pq += v * v;
    }
    s_aux[tid]       = ps;
    s_aux[TPB + tid] = pq;
    __syncthreads();
    if (tid < D) {
        float ss = 0.f, sq = 0.f;
#pragma unroll
        for (int c = 0; c < TPB / D; ++c) {
            ss += s_aux[c * D + tid];
            sq += s_aux[TPB + c * D + tid];
        }
        atomicAdd(&stat_sum[tid], ss);
        atomicAdd(&stat_sq[tid], sq);
    }
}

// ---- REDUCE: dst-segment gather via perm + BN affine + mean ----------
__global__ __launch_bounds__(TPB)
void reduce3_kernel(const float* __restrict__ msg, const int* __restrict__ perm,
                    const int* __restrict__ dst_base,
                    const float* __restrict__ stat_sum, const float* __restrict__ stat_sq,
                    const float* __restrict__ gamma, const float* __restrict__ beta,
                    float invE, int N, float* __restrict__ out)
{
    __shared__ float s_sc[D], s_sh[D];
    const int tid = threadIdx.x;
    if (tid < D) {
        const float mu  = stat_sum[tid] * invE;
        const float var = fmaxf(stat_sq[tid] * invE - mu * mu, 0.f);
        const float is  = rsqrtf(var + EPS);
        const float sc  = gamma[tid] * is;
        s_sc[tid] = sc;
        s_sh[tid] = fmaf(-mu, sc, beta[tid]);
    }
    __syncthreads();
    const int o    = tid & (D - 1);
    const int node = blockIdx.x * (TPB / D) + (tid >> 5);
    if (node >= N) return;
    const int b0 = dst_base[node], b1 = dst_base[node + 1];
    float v = 0.f;
    for (int q = b0; q < b1; ++q) {
        const int pe = perm[q];                    // broadcast within 32-lane group
        v += msg[(size_t)pe * D + o];              // one 128B line per row
    }
    const float c = (float)(b1 - b0);
    out[(size_t)node * D + o] = fmaf(v, s_sc[o], s_sh[o] * c) / fmaxf(c, 1.0f);
}

// ======================================================================
// OLD PATH (fallback when workspace is too small) — unchanged, verified
// ======================================================================

__global__ void hist2_kernel(const int* __restrict__ etype, int E, int R, int chunk,
                             int* __restrict__ blockHistT)   // [R][NB]
{
    __shared__ int lh[1024];
    for (int i = threadIdx.x; i < R; i += TPB) lh[i] = 0;
    __syncthreads();
    const int lo = blockIdx.x * chunk, hi = min(E, lo + chunk);
    for (int e = lo + threadIdx.x; e < hi; e += TPB)
        atomicAdd(&lh[etype[e]], 1);
    __syncthreads();
    for (int r = threadIdx.x; r < R; r += TPB)
        blockHistT[r * NB + blockIdx.x] = lh[r];
}

__global__ void scan2_kernel(int* __restrict__ blockHistT, int R,
                             int* __restrict__ rel_start,
                             int* __restrict__ task_rel, int* __restrict__ task_start,
                             int* __restrict__ n_tasks)
{
    __shared__ int tot[1024];
    __shared__ int s_start[1025];
    __shared__ int s_tbase[1024];
    const int r = threadIdx.x;
    if (r < R) {
        int acc = 0;
        int* p = blockHistT + r * NB;
        for (int b = 0; b < NB; ++b) { int v = p[b]; p[b] = acc; acc += v; }
        tot[r] = acc;
    }
    __syncthreads();
    if (threadIdx.x == 0) {
        int acc = 0, tb = 0;
        for (int rr = 0; rr < R; ++rr) {
            s_start[rr] = acc; s_tbase[rr] = tb;
            acc += tot[rr];
            tb  += (tot[rr] + TPB - 1) / TPB;
        }
        s_start[R] = acc;
        rel_start[R] = acc;
        *n_tasks = tb;
    }
    __syncthreads();
    if (r < R) {
        const int st = s_start[r];
        rel_start[r] = st;
        const int nb = (tot[r] + TPB - 1) / TPB;
        const int tb = s_tbase[r];
        for (int b = 0; b < nb; ++b) {
            task_rel[tb + b]   = r;
            task_start[tb + b] = st + b * TPB;
        }
    }
}

__global__ void scatter2_kernel(const int* __restrict__ src, const int* __restrict__ dst,
                                const int* __restrict__ etype, int E, int R, int chunk,
                                const int* __restrict__ blockHistT,
                                const int* __restrict__ rel_start,
                                int* __restrict__ ssrc, int* __restrict__ sdst)
{
    __shared__ int cur[1024];
    for (int r = threadIdx.x; r < R; r += TPB)
        cur[r] = rel_start[r] + blockHistT[r * NB + blockIdx.x];
    __syncthreads();
    const int lo = blockIdx.x * chunk, hi = min(E, lo + chunk);
    for (int e = lo + threadIdx.x; e < hi; e += TPB) {
        const int p = atomicAdd(&cur[etype[e]], 1);   // LDS atomic only
        ssrc[p] = src[e];
        sdst[p] = dst[e];
    }
}

__global__ __launch_bounds__(TPB)
void rgcn_main(const float* __restrict__ h, const float* __restrict__ W,
               const int* __restrict__ rel_start,
               const int* __restrict__ task_rel, const int* __restrict__ task_start,
               const int* __restrict__ n_tasks_p,
               const int* __restrict__ ssrc, const int* __restrict__ sdst,
               float* __restrict__ out,
               float* __restrict__ stat_sum, float* __restrict__ stat_sq,
               float* __restrict__ cnt)
{
    __shared__ float s_tile[TPB * 33];
    __shared__ int   s_src[TPB];
    __shared__ int   s_dst[TPB];
    __shared__ float s_aux[2 * TPB];

    const int task = blockIdx.x;
    if (task >= *n_tasks_p) return;
    const int r      = task_rel[task];
    const int start  = task_start[task];
    const int relEnd = rel_start[r + 1];
    const int nE     = min(TPB, relEnd - start);
    const int tid    = threadIdx.x;

    if (tid < nE) {
        s_src[tid] = ssrc[start + tid];
        s_dst[tid] = sdst[start + tid];
    }
    __syncthreads();

    for (int i = tid; i < nE * 8; i += TPB) {
        const int row = i >> 3, seg = i & 7;
        const float4 v = *(const float4*)(h + (size_t)s_src[row] * D + seg * 4);
        float* p = &s_tile[row * 33 + seg * 4];
        p[0] = v.x; p[1] = v.y; p[2] = v.z; p[3] = v.w;
    }
    __syncthreads();

    const float* Wr = W + (size_t)__builtin_amdgcn_readfirstlane(r) * (D * D);

    float acc[D];
#pragma unroll
    for (int o = 0; o < D; ++o) acc[o] = 0.f;

    if (tid < nE) {
#pragma unroll 4
        for (int d = 0; d < D; ++d) {
            const float hd = s_tile[tid * 33 + d];
#pragma unroll
            for (int o = 0; o < D; ++o)
                acc[o] = fmaf(hd, Wr[d * D + o], acc[o]);
        }
#pragma unroll
        for (int o = 0; o < D; ++o) acc[o] = fmaxf(acc[o], 0.f);
        atomicAdd(&cnt[s_dst[tid]], 1.0f);
    }
    __syncthreads();

    if (tid < nE) {
#pragma unroll
        for (int o = 0; o < D; ++o) s_tile[tid * 33 + o] = acc[o];
    }
    __syncthreads();

    float ps = 0.f, pq = 0.f;
    for (int i = tid; i < nE * D; i += TPB) {
        const int row = i >> 5, o = i & 31;
        const float v = s_tile[row * 33 + o];
        atomicAdd(&out[(size_t)s_dst[row] * D + o], v);
        ps += v; pq += v * v;
    }
    s_aux[tid]       = ps;
    s_aux[TPB + tid] = pq;
    __syncthreads();
    if (tid < D) {
        float ss = 0.f, sq = 0.f;
#pragma unroll
        for (int c = 0; c < TPB / D; ++c) {
            ss += s_aux[c * D + tid];
            sq += s_aux[TPB + c * D + tid];
        }
        atomicAdd(&stat_sum[tid], ss);
        atomicAdd(&stat_sq[tid], sq);
    }
}

__global__ void finalize_kernel(float* __restrict__ out, const float* __restrict__ cnt,
                                const float* __restrict__ stat_sum,
                                const float* __restrict__ stat_sq,
                                const float* __restrict__ gamma,
                                const float* __restrict__ beta,
                                float invE, int total)
{
    const int i = blockIdx.x * TPB + threadIdx.x;
    if (i >= total) return;
    const int o    = i & 31;
    const int node = i >> 5;
    const float mu  = stat_sum[o] * invE;
    const float var = fmaxf(stat_sq[o] * invE - mu * mu, 0.f);
    const float is  = rsqrtf(var + EPS);
    const float sc  = gamma[o] * is;
    const float sh  = fmaf(-mu, sc, beta[o]);
    const float c   = cnt[node];
    out[i] = fmaf(out[i], sc, sh * c) / fmaxf(c, 1.0f);
}

// ======================================================================
extern "C" void kernel_launch(void* const* d_in, const int* in_sizes, int n_in,
                              void* d_out, int out_size, void* d_ws, size_t ws_size,
                              hipStream_t stream)
{
    const float* h     = (const float*)d_in[0];
    const float* W     = (const float*)d_in[1];
    const float* gamma = (const float*)d_in[2];
    const float* beta  = (const float*)d_in[3];
    const int*   src   = (const int*)d_in[4];
    const int*   dst   = (const int*)d_in[5];
    const int*   etype = (const int*)d_in[6];
    float* out = (float*)d_out;

    const int E = in_sizes[4];
    const int N = in_sizes[0] / D;
    const int R = in_sizes[1] / (D * D);
    const int T = R + (E + TPB - 1) / TPB;        // max task count
    const int chunk = (E + NB - 1) / NB;

    // ---------------- v4 workspace layout (dword offsets) ----------------
    const size_t o_stat_sum   = 0;
    const size_t o_stat_sq    = o_stat_sum + D;
    const size_t o_cnt        = o_stat_sq + D;
    const size_t zwords       = o_cnt + (size_t)N;          // zeroed prefix
    const size_t o_rel_start  = zwords;
    const size_t o_n_tasks    = o_rel_start + R + 1;
    const size_t o_task_rel   = o_n_tasks + 1;
    const size_t o_task_start = o_task_rel + T;
    const size_t o_blockHistT = o_task_start + T;
    const size_t o_dst_base   = o_blockHistT + (size_t)R * NB;
    const size_t o_cursor_dst = o_dst_base + N + 1;
    const size_t o_ssrc       = o_cursor_dst + N;
    const size_t o_perm       = o_ssrc + (size_t)E;
    const size_t o_msg        = (o_perm + (size_t)E + 3) & ~(size_t)3;   // 16B align
    const size_t total_words  = o_msg + (size_t)E * D;

    if (ws_size >= total_words * 4) {
        // ------------------------- PATH v4 -------------------------------
        float* stat_sum   = (float*)d_ws + o_stat_sum;
        float* stat_sq    = (float*)d_ws + o_stat_sq;
        int*   cnt        = (int*)d_ws + o_cnt;
        int*   rel_start  = (int*)d_ws + o_rel_start;
        int*   n_tasks    = (int*)d_ws + o_n_tasks;
        int*   task_rel   = (int*)d_ws + o_task_rel;
        int*   task_start = (int*)d_ws + o_task_start;
        int*   blockHistT = (int*)d_ws + o_blockHistT;
        int*   dst_base   = (int*)d_ws + o_dst_base;
        int*   cursor_dst = (int*)d_ws + o_cursor_dst;
        int*   ssrc       = (int*)d_ws + o_ssrc;
        int*   perm       = (int*)d_ws + o_perm;
        float* msg        = (float*)d_ws + o_msg;

        hipMemsetAsync(d_ws, 0, zwords * 4, stream);

        hist3_kernel<<<NB, TPB, 0, stream>>>(etype, dst, E, R, chunk,
                                             blockHistT, cnt);
        scan3_kernel<<<1, 1024, 0, stream>>>(blockHistT, R, N, E,
                                             rel_start, task_rel, task_start,
                                             n_tasks, cnt, dst_base, cursor_dst);
        scatter3_kernel<<<NB, TPB, 0, stream>>>(src, dst, etype, E, R, chunk,
                                                blockHistT, rel_start,
                                                cursor_dst, ssrc, perm);
        rgcn_main3<<<T, TPB, 0, stream>>>(h, W, rel_start, task_rel, task_start,
                                          n_tasks, ssrc, msg, stat_sum, stat_sq);
        reduce3_kernel<<<(N + TPB / D - 1) / (TPB / D), TPB, 0, stream>>>(
            msg, perm, dst_base, stat_sum, stat_sq, gamma, beta,
            1.0f / (float)E, N, out);
        return;
    }

    // --------------------------- OLD PATH --------------------------------
    float* stat_sum  = (float*)d_ws;
    float* stat_sq   = stat_sum + D;
    float* cntf      = stat_sq + D;
    int*   rel_start = (int*)(cntf + N);
    int*   n_tasks   = rel_start + R + 1;
    int*   task_rel  = n_tasks + 1;
    int*   task_start= task_rel + T;
    int*   blockHistT= task_start + T;
    int*   ssrc      = blockHistT + R * NB;
    int*   sdst      = ssrc + E;

    hipMemsetAsync(d_ws, 0, sizeof(float) * (size_t)(2 * D + N), stream);
    hipMemsetAsync(d_out, 0, sizeof(float) * (size_t)out_size, stream);

    hist2_kernel<<<NB, TPB, 0, stream>>>(etype, E, R, chunk, blockHistT);
    scan2_kernel<<<1, TPB, 0, stream>>>(blockHistT, R, rel_start,
                                        task_rel, task_start, n_tasks);
    scatter2_kernel<<<NB, TPB, 0, stream>>>(src, dst, etype, E, R, chunk,
                                            blockHistT, rel_start, ssrc, sdst);
    rgcn_main<<<T, TPB, 0, stream>>>(h, W, rel_start, task_rel, task_start,
                                     n_tasks, ssrc, sdst, out,
                                     stat_sum, stat_sq, cntf);
    finalize_kernel<<<(N * D + TPB - 1) / TPB, TPB, 0, stream>>>(
        out, cntf, stat_sum, stat_sq, gamma, beta, 1.0f / (float)E, N * D);
}